// Round 1
// baseline (171.257 us; speedup 1.0000x reference)
//
#include <hip/hip_runtime.h>
#include <hip/hip_bf16.h>
#include <stdint.h>

// Problem constants
#define BB 4
#define CC 128
#define NN 4096
#define NSEG 4
#define SEGLEN (NN / NSEG)   // 1024
#define KVBLK 64

typedef __bf16 bf16_t;
typedef bf16_t bf16x8 __attribute__((ext_vector_type(8)));
typedef float f32x4 __attribute__((ext_vector_type(4)));
typedef unsigned int u32;
typedef unsigned short u16;

__device__ __forceinline__ u16 f2bf(float f) {
  union { float f; u32 u; } v; v.f = f;
  u32 r = v.u + 0x7FFFu + ((v.u >> 16) & 1u);   // RNE
  return (u16)(r >> 16);
}

__device__ __forceinline__ bf16x8 ldfrag(const u16* p) {
  return *reinterpret_cast<const bf16x8*>(p);   // ds_read_b128 (16B aligned by construction)
}

__device__ __forceinline__ f32x4 mfma16(bf16x8 a, bf16x8 b, f32x4 c) {
  return __builtin_amdgcn_mfma_f32_16x16x32_bf16(a, b, c, 0, 0, 0);
}

// ---------------------------------------------------------------------------
// Kernel 1: projections.
//   p=0: theta = th_w * x1 + th_b   -> qws  [B][N][C]  (transposed layout)
//   p=1: phi   = ph_w * x0 + ph_b   -> kws  [B][N][C]
//   p=2: g     = g_w  * x0 + g_b    -> vws  [B][C][N]  (natural layout)
// Both MFMA operand reads want K(=c')-contiguous rows: A=xT [n][c'] / W [c][c'].
// ---------------------------------------------------------------------------
__global__ __launch_bounds__(256) void proj_kernel(
    const float* __restrict__ x0, const float* __restrict__ x1,
    const float* __restrict__ g_w, const float* __restrict__ g_b,
    const float* __restrict__ th_w, const float* __restrict__ th_b,
    const float* __restrict__ ph_w, const float* __restrict__ ph_b,
    u16* __restrict__ qws, u16* __restrict__ kws, u16* __restrict__ vws)
{
  const int t = threadIdx.x;
  const int nt0 = blockIdx.x * 64;   // n-tile base
  const int b = blockIdx.y;
  const int p = blockIdx.z;          // 0=theta 1=phi 2=g

  __shared__ __align__(16) u16 W_lds[128][136];  // [c][c'] bf16, pad 8
  __shared__ __align__(16) u16 xT_lds[64][136];  // [n][c'] bf16, pad 8

  const float* x    = (p == 0) ? x1 : x0;
  const float* w    = (p == 0) ? th_w : (p == 1) ? ph_w : g_w;
  const float* bias = (p == 0) ? th_b : (p == 1) ? ph_b : g_b;

  // stage W (f32 -> bf16), coalesced float4 reads
  for (int i = 0; i < 16; ++i) {
    int s = t + i * 256;             // 4096 float4 slots
    int row = s >> 5, c4 = s & 31;
    float4 v = *reinterpret_cast<const float4*>(w + row * 128 + c4 * 4);
    u32 lo = (u32)f2bf(v.x) | ((u32)f2bf(v.y) << 16);
    u32 hi = (u32)f2bf(v.z) | ((u32)f2bf(v.w) << 16);
    *reinterpret_cast<uint2*>(&W_lds[row][c4 * 4]) = make_uint2(lo, hi);
  }
  // stage xT: read x[b][c'][n] coalesced along n, write transposed
  for (int i = 0; i < 8; ++i) {
    int s = t + i * 256;             // 2048 float4 slots
    int cp = s >> 4;                 // c' row
    int nc = s & 15;                 // n chunk of 4
    float4 v = *reinterpret_cast<const float4*>(x + ((size_t)b * CC + cp) * NN + nt0 + nc * 4);
    xT_lds[nc * 4 + 0][cp] = f2bf(v.x);
    xT_lds[nc * 4 + 1][cp] = f2bf(v.y);
    xT_lds[nc * 4 + 2][cp] = f2bf(v.z);
    xT_lds[nc * 4 + 3][cp] = f2bf(v.w);
  }
  __syncthreads();

  const int w_id = t >> 6, l = t & 63;
  const int lr = l & 15, lh = l >> 4;

  if (p < 2) {
    // D[n][c] tile 64x128; wave owns 16 n-rows
    f32x4 acc[8];
#pragma unroll
    for (int ct = 0; ct < 8; ++ct) acc[ct] = (f32x4){0.f, 0.f, 0.f, 0.f};
#pragma unroll
    for (int kc = 0; kc < 4; ++kc) {
      bf16x8 a = ldfrag(&xT_lds[w_id * 16 + lr][kc * 32 + lh * 8]);
#pragma unroll
      for (int ct = 0; ct < 8; ++ct) {
        bf16x8 bf = ldfrag(&W_lds[ct * 16 + lr][kc * 32 + lh * 8]);
        acc[ct] = mfma16(a, bf, acc[ct]);
      }
    }
    u16* outp = (p == 0) ? qws : kws;
#pragma unroll
    for (int ct = 0; ct < 8; ++ct) {
      float bv = bias[ct * 16 + lr];
#pragma unroll
      for (int r = 0; r < 4; ++r) {
        int n = nt0 + w_id * 16 + lh * 4 + r;
        outp[((size_t)b * NN + n) * CC + ct * 16 + lr] = f2bf(acc[ct][r] + bv);
      }
    }
  } else {
    // D[c][n] tile 128x64; wave owns 32 c-rows
    f32x4 acc[2][4];
#pragma unroll
    for (int rt = 0; rt < 2; ++rt)
#pragma unroll
      for (int nt = 0; nt < 4; ++nt) acc[rt][nt] = (f32x4){0.f, 0.f, 0.f, 0.f};
#pragma unroll
    for (int kc = 0; kc < 4; ++kc) {
      bf16x8 a0 = ldfrag(&W_lds[w_id * 32 + lr][kc * 32 + lh * 8]);
      bf16x8 a1 = ldfrag(&W_lds[w_id * 32 + 16 + lr][kc * 32 + lh * 8]);
#pragma unroll
      for (int nt = 0; nt < 4; ++nt) {
        bf16x8 bf = ldfrag(&xT_lds[nt * 16 + lr][kc * 32 + lh * 8]);
        acc[0][nt] = mfma16(a0, bf, acc[0][nt]);
        acc[1][nt] = mfma16(a1, bf, acc[1][nt]);
      }
    }
#pragma unroll
    for (int rt = 0; rt < 2; ++rt)
#pragma unroll
      for (int r = 0; r < 4; ++r) {
        int c = w_id * 32 + rt * 16 + lh * 4 + r;
        float bv = bias[c];
#pragma unroll
        for (int nt = 0; nt < 4; ++nt) {
          vws[((size_t)b * CC + c) * NN + nt0 + nt * 16 + lr] = f2bf(acc[rt][nt][r] + bv);
        }
      }
  }
}

// ---------------------------------------------------------------------------
// Kernel 2: flash attention with KV-split (NSEG segments of 1024 keys).
// Block: 4 waves x 16 q-rows = 64 queries. Writes unnormalized y + (m,l).
// ---------------------------------------------------------------------------
__global__ __launch_bounds__(256) void attn_kernel(
    const u16* __restrict__ qws, const u16* __restrict__ kws,
    const u16* __restrict__ vws, float* __restrict__ yacc,
    float* __restrict__ ml)
{
  const int t = threadIdx.x, w_id = t >> 6, l = t & 63;
  const int lr = l & 15, lh = l >> 4;
  const int q0 = blockIdx.x * 64;
  const int b = blockIdx.y;
  const int seg = blockIdx.z;
  const int m_base = seg * SEGLEN;

  __shared__ __align__(16) u16 K_lds[64][136];     // [key][c] pad 8
  __shared__ __align__(16) u16 Vt_lds[128][72];    // [c][key] pad 8 (row copy of g[B][C][N])
  __shared__ __align__(16) u16 P_lds[4][16][72];   // per-wave [q][key] pad 8

  // preload Q fragments (A-operand: row = lr, k = lh*8+j per 32-k chunk)
  bf16x8 qf[4];
  {
    const u16* qp = qws + ((size_t)b * NN + q0 + w_id * 16 + lr) * CC;
#pragma unroll
    for (int kc = 0; kc < 4; ++kc)
      qf[kc] = *reinterpret_cast<const bf16x8*>(qp + kc * 32 + lh * 8);
  }

  f32x4 acc[8];
#pragma unroll
  for (int ct = 0; ct < 8; ++ct) acc[ct] = (f32x4){0.f, 0.f, 0.f, 0.f};
  float m_run[4], l_run[4];
#pragma unroll
  for (int r = 0; r < 4; ++r) { m_run[r] = -1e30f; l_run[r] = 0.f; }

  for (int ch = 0; ch < SEGLEN / KVBLK; ++ch) {
    const int m0 = m_base + ch * KVBLK;
    __syncthreads();   // protect previous iteration's LDS consumers
    // stage K chunk [64][128]
#pragma unroll
    for (int i = 0; i < 4; ++i) {
      int s = t + i * 256; int row = s >> 4, cc8 = s & 15;
      uint4 v = *reinterpret_cast<const uint4*>(kws + ((size_t)b * NN + m0 + row) * CC + cc8 * 8);
      *reinterpret_cast<uint4*>(&K_lds[row][cc8 * 8]) = v;
    }
    // stage Vt chunk [128][64] — straight row copy from g[B][C][N]
#pragma unroll
    for (int i = 0; i < 4; ++i) {
      int s = t + i * 256; int c = s >> 3, mc = s & 7;
      uint4 v = *reinterpret_cast<const uint4*>(vws + ((size_t)b * CC + c) * NN + m0 + mc * 8);
      *reinterpret_cast<uint4*>(&Vt_lds[c][mc * 8]) = v;
    }
    __syncthreads();

    // QK^T: S[16q][64k]
    f32x4 s_acc[4];
#pragma unroll
    for (int kt = 0; kt < 4; ++kt) s_acc[kt] = (f32x4){0.f, 0.f, 0.f, 0.f};
#pragma unroll
    for (int kc = 0; kc < 4; ++kc) {
#pragma unroll
      for (int kt = 0; kt < 4; ++kt) {
        bf16x8 kb = ldfrag(&K_lds[kt * 16 + lr][kc * 32 + lh * 8]);
        s_acc[kt] = mfma16(qf[kc], kb, s_acc[kt]);
      }
    }

    // online softmax (rows = lh*4+r; cols spread over 16 lanes of the lh-group)
    float scale_[4];
#pragma unroll
    for (int r = 0; r < 4; ++r) {
      float mx = fmaxf(fmaxf(s_acc[0][r], s_acc[1][r]), fmaxf(s_acc[2][r], s_acc[3][r]));
      mx = fmaxf(mx, __shfl_xor(mx, 1));
      mx = fmaxf(mx, __shfl_xor(mx, 2));
      mx = fmaxf(mx, __shfl_xor(mx, 4));
      mx = fmaxf(mx, __shfl_xor(mx, 8));
      float mnew = fmaxf(m_run[r], mx);
      scale_[r] = __expf(m_run[r] - mnew);
      m_run[r] = mnew;
    }
#pragma unroll
    for (int kt = 0; kt < 4; ++kt) {
#pragma unroll
      for (int r = 0; r < 4; ++r) {
        float pv = __expf(s_acc[kt][r] - m_run[r]);
        s_acc[kt][r] = pv;
        P_lds[w_id][lh * 4 + r][kt * 16 + lr] = f2bf(pv);
      }
    }
#pragma unroll
    for (int r = 0; r < 4; ++r) {
      float ps = s_acc[0][r] + s_acc[1][r] + s_acc[2][r] + s_acc[3][r];
      ps += __shfl_xor(ps, 1);
      ps += __shfl_xor(ps, 2);
      ps += __shfl_xor(ps, 4);
      ps += __shfl_xor(ps, 8);
      l_run[r] = l_run[r] * scale_[r] + ps;
    }
#pragma unroll
    for (int ct = 0; ct < 8; ++ct)
#pragma unroll
      for (int r = 0; r < 4; ++r) acc[ct][r] *= scale_[r];

    // PV: y[16q][128c] += P[16q][64k] * V[64k][128c]
#pragma unroll
    for (int kh = 0; kh < 2; ++kh) {
      bf16x8 pa = ldfrag(&P_lds[w_id][lr][kh * 32 + lh * 8]);
#pragma unroll
      for (int ct = 0; ct < 8; ++ct) {
        bf16x8 vb = ldfrag(&Vt_lds[ct * 16 + lr][kh * 32 + lh * 8]);
        acc[ct] = mfma16(pa, vb, acc[ct]);
      }
    }
  }

  // epilogue: unnormalized partials
  const size_t rb = ((size_t)(b * NSEG + seg) * NN + q0 + w_id * 16);
#pragma unroll
  for (int ct = 0; ct < 8; ++ct)
#pragma unroll
    for (int r = 0; r < 4; ++r)
      yacc[(rb + lh * 4 + r) * CC + ct * 16 + lr] = acc[ct][r];
  if (lr == 0) {
#pragma unroll
    for (int r = 0; r < 4; ++r) {
      ml[(rb + lh * 4 + r) * 2 + 0] = m_run[r];
      ml[(rb + lh * 4 + r) * 2 + 1] = l_run[r];
    }
  }
}

// ---------------------------------------------------------------------------
// Kernel 3: combine NSEG partials -> y bf16 [B][N][C]
// ---------------------------------------------------------------------------
__global__ __launch_bounds__(256) void combine_kernel(
    const float* __restrict__ yacc, const float* __restrict__ ml,
    u16* __restrict__ ybf)
{
  const int t = threadIdx.x;
  const int rr = blockIdx.x * 16 + (t >> 4);   // global row 0..16383
  const int li = t & 15;
  const int b = rr >> 12, n = rr & (NN - 1);

  float m_s[NSEG], l_s[NSEG];
#pragma unroll
  for (int s = 0; s < NSEG; ++s) {
    size_t base = ((size_t)(b * NSEG + s) * NN + n);
    m_s[s] = ml[base * 2];
    l_s[s] = ml[base * 2 + 1];
  }
  float M = fmaxf(fmaxf(m_s[0], m_s[1]), fmaxf(m_s[2], m_s[3]));
  float wgt[NSEG]; float denom = 0.f;
#pragma unroll
  for (int s = 0; s < NSEG; ++s) { wgt[s] = __expf(m_s[s] - M); denom += wgt[s] * l_s[s]; }
  const float inv = 1.0f / denom;

  float o[8];
#pragma unroll
  for (int j = 0; j < 8; ++j) o[j] = 0.f;
#pragma unroll
  for (int s = 0; s < NSEG; ++s) {
    const float4* yp = reinterpret_cast<const float4*>(
        yacc + ((size_t)(b * NSEG + s) * NN + n) * CC + li * 8);
    float4 a = yp[0], c = yp[1];
    float w = wgt[s];
    o[0] += w * a.x; o[1] += w * a.y; o[2] += w * a.z; o[3] += w * a.w;
    o[4] += w * c.x; o[5] += w * c.y; o[6] += w * c.z; o[7] += w * c.w;
  }
  u32 p0 = (u32)f2bf(o[0] * inv) | ((u32)f2bf(o[1] * inv) << 16);
  u32 p1 = (u32)f2bf(o[2] * inv) | ((u32)f2bf(o[3] * inv) << 16);
  u32 p2 = (u32)f2bf(o[4] * inv) | ((u32)f2bf(o[5] * inv) << 16);
  u32 p3 = (u32)f2bf(o[6] * inv) | ((u32)f2bf(o[7] * inv) << 16);
  *reinterpret_cast<uint4*>(ybf + ((size_t)b * NN + n) * CC + li * 8) = make_uint4(p0, p1, p2, p3);
}

// ---------------------------------------------------------------------------
// Kernel 4: out = W_w * y + W_b  -> d_out f32 [B][C][N]
// ---------------------------------------------------------------------------
__global__ __launch_bounds__(256) void outproj_kernel(
    const u16* __restrict__ ybf, const float* __restrict__ Ww,
    const float* __restrict__ Wb, float* __restrict__ out)
{
  const int t = threadIdx.x;
  const int nt0 = blockIdx.x * 64;
  const int b = blockIdx.y;

  __shared__ __align__(16) u16 W_lds[128][136];
  __shared__ __align__(16) u16 y_lds[64][136];

  for (int i = 0; i < 16; ++i) {
    int s = t + i * 256;
    int row = s >> 5, c4 = s & 31;
    float4 v = *reinterpret_cast<const float4*>(Ww + row * 128 + c4 * 4);
    u32 lo = (u32)f2bf(v.x) | ((u32)f2bf(v.y) << 16);
    u32 hi = (u32)f2bf(v.z) | ((u32)f2bf(v.w) << 16);
    *reinterpret_cast<uint2*>(&W_lds[row][c4 * 4]) = make_uint2(lo, hi);
  }
#pragma unroll
  for (int i = 0; i < 4; ++i) {
    int s = t + i * 256; int row = s >> 4, cc8 = s & 15;
    uint4 v = *reinterpret_cast<const uint4*>(ybf + ((size_t)b * NN + nt0 + row) * CC + cc8 * 8);
    *reinterpret_cast<uint4*>(&y_lds[row][cc8 * 8]) = v;
  }
  __syncthreads();

  const int w_id = t >> 6, l = t & 63;
  const int lr = l & 15, lh = l >> 4;

  f32x4 acc[2][4];
#pragma unroll
  for (int rt = 0; rt < 2; ++rt)
#pragma unroll
    for (int nt = 0; nt < 4; ++nt) acc[rt][nt] = (f32x4){0.f, 0.f, 0.f, 0.f};
#pragma unroll
  for (int kc = 0; kc < 4; ++kc) {
    bf16x8 a0 = ldfrag(&W_lds[w_id * 32 + lr][kc * 32 + lh * 8]);
    bf16x8 a1 = ldfrag(&W_lds[w_id * 32 + 16 + lr][kc * 32 + lh * 8]);
#pragma unroll
    for (int nt = 0; nt < 4; ++nt) {
      bf16x8 bf = ldfrag(&y_lds[nt * 16 + lr][kc * 32 + lh * 8]);
      acc[0][nt] = mfma16(a0, bf, acc[0][nt]);
      acc[1][nt] = mfma16(a1, bf, acc[1][nt]);
    }
  }
#pragma unroll
  for (int rt = 0; rt < 2; ++rt)
#pragma unroll
    for (int r = 0; r < 4; ++r) {
      int c = w_id * 32 + rt * 16 + lh * 4 + r;
      float bv = Wb[c];
#pragma unroll
      for (int nt = 0; nt < 4; ++nt)
        out[((size_t)b * CC + c) * NN + nt0 + nt * 16 + lr] = acc[rt][nt][r] + bv;
    }
}

// ---------------------------------------------------------------------------
extern "C" void kernel_launch(void* const* d_in, const int* in_sizes, int n_in,
                              void* d_out, int out_size, void* d_ws, size_t ws_size,
                              hipStream_t stream) {
  const float* x0   = (const float*)d_in[0];
  const float* x1   = (const float*)d_in[1];
  const float* g_w  = (const float*)d_in[2];
  const float* g_b  = (const float*)d_in[3];
  const float* th_w = (const float*)d_in[4];
  const float* th_b = (const float*)d_in[5];
  const float* ph_w = (const float*)d_in[6];
  const float* ph_b = (const float*)d_in[7];
  const float* Ww   = (const float*)d_in[8];
  const float* Wb   = (const float*)d_in[9];

  char* ws = (char*)d_ws;
  // layout: q(4MiB) k(4MiB) v(4MiB) ybf(4MiB) yacc(32MiB) ml(0.5MiB)
  u16* qws   = (u16*)(ws + 0);
  u16* kws   = (u16*)(ws + (size_t)4194304);
  u16* vws   = (u16*)(ws + (size_t)8388608);
  u16* ybf   = (u16*)(ws + (size_t)12582912);
  float* yacc = (float*)(ws + (size_t)16777216);
  float* mlp  = (float*)(ws + (size_t)50331648);

  dim3 gp(64, 4, 3);
  proj_kernel<<<gp, 256, 0, stream>>>(x0, x1, g_w, g_b, th_w, th_b, ph_w, ph_b,
                                      qws, kws, vws);
  dim3 ga(64, 4, 4);
  attn_kernel<<<ga, 256, 0, stream>>>(qws, kws, vws, yacc, mlp);
  combine_kernel<<<1024, 256, 0, stream>>>(yacc, mlp, ybf);
  dim3 go(64, 4);
  outproj_kernel<<<go, 256, 0, stream>>>(ybf, Ww, Wb, (float*)d_out);
}

// Round 2
// 112.243 us; speedup vs baseline: 1.5258x; 1.5258x over previous
//
#include <hip/hip_runtime.h>
#include <hip/hip_bf16.h>
#include <stdint.h>

// Problem constants
#define BB 4
#define CC 128
#define NN 4096
#define NSEG 4
#define SEGLEN (NN / NSEG)   // 1024
#define KVBLK 64

typedef __bf16 bf16_t;
typedef bf16_t bf16x8 __attribute__((ext_vector_type(8)));
typedef float f32x4 __attribute__((ext_vector_type(4)));
typedef float f32x16 __attribute__((ext_vector_type(16)));
typedef int v2i __attribute__((ext_vector_type(2)));
typedef unsigned int u32;
typedef unsigned short u16;

__device__ __forceinline__ u16 f2bf(float f) {
  union { float f; u32 u; } v; v.f = f;
  u32 r = v.u + 0x7FFFu + ((v.u >> 16) & 1u);   // RNE
  return (u16)(r >> 16);
}

__device__ __forceinline__ bf16x8 ldfrag(const u16* p) {
  return *reinterpret_cast<const bf16x8*>(p);   // ds_read_b128
}

__device__ __forceinline__ f32x4 mfma16(bf16x8 a, bf16x8 b, f32x4 c) {
  return __builtin_amdgcn_mfma_f32_16x16x32_bf16(a, b, c, 0, 0, 0);
}
__device__ __forceinline__ f32x16 mfma32(bf16x8 a, bf16x8 b, f32x16 c) {
  return __builtin_amdgcn_mfma_f32_32x32x16_bf16(a, b, c, 0, 0, 0);
}
__device__ __forceinline__ u32 cvtpk(float lo, float hi) {
  u32 d; asm("v_cvt_pk_bf16_f32 %0, %1, %2" : "=v"(d) : "v"(lo), "v"(hi)); return d;
}

// ---------------------------------------------------------------------------
// Kernel 1: projections (unchanged from round 1).
//   p=0: theta -> qws [B][N][C];  p=1: phi -> kws [B][N][C];  p=2: g -> vws [B][C][N]
// ---------------------------------------------------------------------------
__global__ __launch_bounds__(256) void proj_kernel(
    const float* __restrict__ x0, const float* __restrict__ x1,
    const float* __restrict__ g_w, const float* __restrict__ g_b,
    const float* __restrict__ th_w, const float* __restrict__ th_b,
    const float* __restrict__ ph_w, const float* __restrict__ ph_b,
    u16* __restrict__ qws, u16* __restrict__ kws, u16* __restrict__ vws)
{
  const int t = threadIdx.x;
  const int nt0 = blockIdx.x * 64;
  const int b = blockIdx.y;
  const int p = blockIdx.z;

  __shared__ __align__(16) u16 W_lds[128][136];
  __shared__ __align__(16) u16 xT_lds[64][136];

  const float* x    = (p == 0) ? x1 : x0;
  const float* w    = (p == 0) ? th_w : (p == 1) ? ph_w : g_w;
  const float* bias = (p == 0) ? th_b : (p == 1) ? ph_b : g_b;

  for (int i = 0; i < 16; ++i) {
    int s = t + i * 256;
    int row = s >> 5, c4 = s & 31;
    float4 v = *reinterpret_cast<const float4*>(w + row * 128 + c4 * 4);
    u32 lo = (u32)f2bf(v.x) | ((u32)f2bf(v.y) << 16);
    u32 hi = (u32)f2bf(v.z) | ((u32)f2bf(v.w) << 16);
    *reinterpret_cast<uint2*>(&W_lds[row][c4 * 4]) = make_uint2(lo, hi);
  }
  for (int i = 0; i < 8; ++i) {
    int s = t + i * 256;
    int cp = s >> 4;
    int nc = s & 15;
    float4 v = *reinterpret_cast<const float4*>(x + ((size_t)b * CC + cp) * NN + nt0 + nc * 4);
    xT_lds[nc * 4 + 0][cp] = f2bf(v.x);
    xT_lds[nc * 4 + 1][cp] = f2bf(v.y);
    xT_lds[nc * 4 + 2][cp] = f2bf(v.z);
    xT_lds[nc * 4 + 3][cp] = f2bf(v.w);
  }
  __syncthreads();

  const int w_id = t >> 6, l = t & 63;
  const int lr = l & 15, lh = l >> 4;

  if (p < 2) {
    f32x4 acc[8];
#pragma unroll
    for (int ct = 0; ct < 8; ++ct) acc[ct] = (f32x4){0.f, 0.f, 0.f, 0.f};
#pragma unroll
    for (int kc = 0; kc < 4; ++kc) {
      bf16x8 a = ldfrag(&xT_lds[w_id * 16 + lr][kc * 32 + lh * 8]);
#pragma unroll
      for (int ct = 0; ct < 8; ++ct) {
        bf16x8 bf = ldfrag(&W_lds[ct * 16 + lr][kc * 32 + lh * 8]);
        acc[ct] = mfma16(a, bf, acc[ct]);
      }
    }
    u16* outp = (p == 0) ? qws : kws;
#pragma unroll
    for (int ct = 0; ct < 8; ++ct) {
      float bv = bias[ct * 16 + lr];
#pragma unroll
      for (int r = 0; r < 4; ++r) {
        int n = nt0 + w_id * 16 + lh * 4 + r;
        outp[((size_t)b * NN + n) * CC + ct * 16 + lr] = f2bf(acc[ct][r] + bv);
      }
    }
  } else {
    f32x4 acc[2][4];
#pragma unroll
    for (int rt = 0; rt < 2; ++rt)
#pragma unroll
      for (int nt = 0; nt < 4; ++nt) acc[rt][nt] = (f32x4){0.f, 0.f, 0.f, 0.f};
#pragma unroll
    for (int kc = 0; kc < 4; ++kc) {
      bf16x8 a0 = ldfrag(&W_lds[w_id * 32 + lr][kc * 32 + lh * 8]);
      bf16x8 a1 = ldfrag(&W_lds[w_id * 32 + 16 + lr][kc * 32 + lh * 8]);
#pragma unroll
      for (int nt = 0; nt < 4; ++nt) {
        bf16x8 bf = ldfrag(&xT_lds[nt * 16 + lr][kc * 32 + lh * 8]);
        acc[0][nt] = mfma16(a0, bf, acc[0][nt]);
        acc[1][nt] = mfma16(a1, bf, acc[1][nt]);
      }
    }
#pragma unroll
    for (int rt = 0; rt < 2; ++rt)
#pragma unroll
      for (int r = 0; r < 4; ++r) {
        int c = w_id * 32 + rt * 16 + lh * 4 + r;
        float bv = bias[c];
#pragma unroll
        for (int nt = 0; nt < 4; ++nt) {
          vws[((size_t)b * CC + c) * NN + nt0 + nt * 16 + lr] = f2bf(acc[rt][nt][r] + bv);
        }
      }
  }
}

// ---------------------------------------------------------------------------
// Kernel 2: flash attention, 32x32 MFMA, swapped-QK^T, in-register softmax.
// Block: 4 waves x 32 q-rows = 128 queries. KV-split NSEG segments.
// Per-lane: q = lane&31, full P row held across lane pair (lane, lane^32).
// ---------------------------------------------------------------------------
__global__ __launch_bounds__(256, 2) void attn_kernel(
    const u16* __restrict__ qws, const u16* __restrict__ kws,
    const u16* __restrict__ vws, float* __restrict__ yacc,
    float* __restrict__ ml)
{
  const int t = threadIdx.x, wv = t >> 6, l = t & 63;
  const int l31 = l & 31, hi = l >> 5;
  const int q0 = blockIdx.x * 128;
  const int b = blockIdx.y, seg = blockIdx.z;
  constexpr int NCH = SEGLEN / KVBLK;

  __shared__ __align__(16) u16 K_lds[64][136];    // [key][c], pad 16B
  __shared__ __align__(16) u16 Vt_lds[128][72];   // [c][key], pad 16B

  // Q fragments: lane holds Q[q=l31][kc*16 + hi*8 .. +7] for kc=0..7 (32 VGPRs)
  bf16x8 qf[8];
  {
    const u16* qp = qws + ((size_t)b * NN + q0 + wv * 32 + l31) * CC + hi * 8;
#pragma unroll
    for (int kc = 0; kc < 8; ++kc) qf[kc] = *reinterpret_cast<const bf16x8*>(qp + kc * 16);
  }

  // staging geometry (per thread, 4 x uint4 each for K and V)
  int kr[4], kc8[4], vc[4], vm8[4];
#pragma unroll
  for (int i = 0; i < 4; ++i) {
    int s = t + i * 256;
    kr[i] = s >> 4; kc8[i] = (s & 15) * 8;
    vc[i] = s >> 3; vm8[i] = (s & 7) * 8;
  }
  const u16* kg = kws + ((size_t)b * NN + seg * SEGLEN) * CC;
  const u16* vg = vws + (size_t)b * CC * NN + seg * SEGLEN;
  uint4 kreg[4], vreg[4];
#pragma unroll
  for (int i = 0; i < 4; ++i) kreg[i] = *reinterpret_cast<const uint4*>(kg + (size_t)kr[i] * CC + kc8[i]);
#pragma unroll
  for (int i = 0; i < 4; ++i) vreg[i] = *reinterpret_cast<const uint4*>(vg + (size_t)vc[i] * NN + vm8[i]);

  f32x16 yt[4];
#pragma unroll
  for (int ct = 0; ct < 4; ++ct)
#pragma unroll
    for (int r = 0; r < 16; ++r) yt[ct][r] = 0.f;
  float m_run = -1e30f, l_run = 0.f;

  for (int ch = 0; ch < NCH; ++ch) {
    __syncthreads();   // previous chunk's LDS consumers done
#pragma unroll
    for (int i = 0; i < 4; ++i) *reinterpret_cast<uint4*>(&K_lds[kr[i]][kc8[i]]) = kreg[i];
#pragma unroll
    for (int i = 0; i < 4; ++i) *reinterpret_cast<uint4*>(&Vt_lds[vc[i]][vm8[i]]) = vreg[i];
    if (ch + 1 < NCH) {   // prefetch next chunk; latency hides under compute below
      kg += KVBLK * CC; vg += KVBLK;
#pragma unroll
      for (int i = 0; i < 4; ++i) kreg[i] = *reinterpret_cast<const uint4*>(kg + (size_t)kr[i] * CC + kc8[i]);
#pragma unroll
      for (int i = 0; i < 4; ++i) vreg[i] = *reinterpret_cast<const uint4*>(vg + (size_t)vc[i] * NN + vm8[i]);
    }
    __syncthreads();

    // --- swapped QK^T: S^T[k][q] = K . Q^T ; lane holds 32 k-values for q=l31
    f32x16 st0, st1;
#pragma unroll
    for (int r = 0; r < 16; ++r) { st0[r] = 0.f; st1[r] = 0.f; }
    __builtin_amdgcn_s_setprio(1);
#pragma unroll
    for (int kc = 0; kc < 8; ++kc) {
      bf16x8 a0 = ldfrag(&K_lds[l31][kc * 16 + hi * 8]);
      bf16x8 a1 = ldfrag(&K_lds[32 + l31][kc * 16 + hi * 8]);
      st0 = mfma32(a0, qf[kc], st0);
      st1 = mfma32(a1, qf[kc], st1);
    }
    __builtin_amdgcn_s_setprio(0);

    // --- online softmax, fully in-register
    float mx = st0[0];
#pragma unroll
    for (int r = 1; r < 16; ++r) mx = fmaxf(mx, st0[r]);
#pragma unroll
    for (int r = 0; r < 16; ++r) mx = fmaxf(mx, st1[r]);
    {
      v2i rr = __builtin_amdgcn_permlane32_swap(__float_as_int(mx), __float_as_int(mx), false, false);
      mx = fmaxf(__int_as_float(rr.x), __int_as_float(rr.y));
    }
    if (!__all(mx - m_run <= 8.f)) {   // defer-max (T13): rescale only on real growth
      float mnew = fmaxf(m_run, mx);
      float sc = __expf(m_run - mnew);
      l_run *= sc;
#pragma unroll
      for (int ct = 0; ct < 4; ++ct)
#pragma unroll
        for (int r = 0; r < 16; ++r) yt[ct][r] *= sc;
      m_run = mnew;
    }
    float ps = 0.f;
#pragma unroll
    for (int r = 0; r < 16; ++r) { st0[r] = __expf(st0[r] - m_run); ps += st0[r]; }
#pragma unroll
    for (int r = 0; r < 16; ++r) { st1[r] = __expf(st1[r] - m_run); ps += st1[r]; }
    {
      v2i rr = __builtin_amdgcn_permlane32_swap(__float_as_int(ps), __float_as_int(ps), false, false);
      ps = __int_as_float(rr.x) + __int_as_float(rr.y);
    }
    l_run += ps;

    // --- PV: y^T[c][q] += V^T . P^T.  B-frags of P^T built via cvt_pk+permlane (T12)
    __builtin_amdgcn_s_setprio(1);
#define PV_KC2(SS, KC2) do {                                                        \
      u32 X0 = cvtpk(SS[(((KC2)&1)*8)+0], SS[(((KC2)&1)*8)+1]);                     \
      u32 X1 = cvtpk(SS[(((KC2)&1)*8)+2], SS[(((KC2)&1)*8)+3]);                     \
      u32 X4 = cvtpk(SS[(((KC2)&1)*8)+4], SS[(((KC2)&1)*8)+5]);                     \
      u32 X5 = cvtpk(SS[(((KC2)&1)*8)+6], SS[(((KC2)&1)*8)+7]);                     \
      v2i s1 = __builtin_amdgcn_permlane32_swap((int)X0, (int)X4, false, false);    \
      v2i s2 = __builtin_amdgcn_permlane32_swap((int)X1, (int)X5, false, false);    \
      int4 bw = make_int4(s1.x, s2.x, s1.y, s2.y);                                  \
      bf16x8 pb = *reinterpret_cast<bf16x8*>(&bw);                                  \
      _Pragma("unroll")                                                             \
      for (int ct = 0; ct < 4; ++ct) {                                              \
        bf16x8 va = ldfrag(&Vt_lds[ct * 32 + l31][(KC2) * 16 + hi * 8]);            \
        yt[ct] = mfma32(va, pb, yt[ct]);                                            \
      }                                                                             \
    } while (0)
    PV_KC2(st0, 0);
    PV_KC2(st0, 1);
    PV_KC2(st1, 2);
    PV_KC2(st1, 3);
#undef PV_KC2
    __builtin_amdgcn_s_setprio(0);
  }

  // epilogue: unnormalized y^T partials -> yacc [b*NSEG+seg][q][c]
  const size_t row_g = (size_t)(b * NSEG + seg) * NN + q0 + wv * 32 + l31;
  float* yp = yacc + row_g * CC;
#pragma unroll
  for (int ct = 0; ct < 4; ++ct)
#pragma unroll
    for (int g = 0; g < 4; ++g) {
      f32x4 v = { yt[ct][4 * g + 0], yt[ct][4 * g + 1], yt[ct][4 * g + 2], yt[ct][4 * g + 3] };
      *reinterpret_cast<f32x4*>(yp + ct * 32 + g * 8 + hi * 4) = v;
    }
  if (l < 32) {
    ml[row_g * 2 + 0] = m_run;
    ml[row_g * 2 + 1] = l_run;
  }
}

// ---------------------------------------------------------------------------
// Kernel 3: combine NSEG partials -> y bf16 [B][N][C] (unchanged)
// ---------------------------------------------------------------------------
__global__ __launch_bounds__(256) void combine_kernel(
    const float* __restrict__ yacc, const float* __restrict__ ml,
    u16* __restrict__ ybf)
{
  const int t = threadIdx.x;
  const int rr = blockIdx.x * 16 + (t >> 4);
  const int li = t & 15;
  const int b = rr >> 12, n = rr & (NN - 1);

  float m_s[NSEG], l_s[NSEG];
#pragma unroll
  for (int s = 0; s < NSEG; ++s) {
    size_t base = ((size_t)(b * NSEG + s) * NN + n);
    m_s[s] = ml[base * 2];
    l_s[s] = ml[base * 2 + 1];
  }
  float M = fmaxf(fmaxf(m_s[0], m_s[1]), fmaxf(m_s[2], m_s[3]));
  float wgt[NSEG]; float denom = 0.f;
#pragma unroll
  for (int s = 0; s < NSEG; ++s) { wgt[s] = __expf(m_s[s] - M); denom += wgt[s] * l_s[s]; }
  const float inv = 1.0f / denom;

  float o[8];
#pragma unroll
  for (int j = 0; j < 8; ++j) o[j] = 0.f;
#pragma unroll
  for (int s = 0; s < NSEG; ++s) {
    const float4* yp = reinterpret_cast<const float4*>(
        yacc + ((size_t)(b * NSEG + s) * NN + n) * CC + li * 8);
    float4 a = yp[0], c = yp[1];
    float w = wgt[s];
    o[0] += w * a.x; o[1] += w * a.y; o[2] += w * a.z; o[3] += w * a.w;
    o[4] += w * c.x; o[5] += w * c.y; o[6] += w * c.z; o[7] += w * c.w;
  }
  u32 p0 = (u32)f2bf(o[0] * inv) | ((u32)f2bf(o[1] * inv) << 16);
  u32 p1 = (u32)f2bf(o[2] * inv) | ((u32)f2bf(o[3] * inv) << 16);
  u32 p2 = (u32)f2bf(o[4] * inv) | ((u32)f2bf(o[5] * inv) << 16);
  u32 p3 = (u32)f2bf(o[6] * inv) | ((u32)f2bf(o[7] * inv) << 16);
  *reinterpret_cast<uint4*>(ybf + ((size_t)b * NN + n) * CC + li * 8) = make_uint4(p0, p1, p2, p3);
}

// ---------------------------------------------------------------------------
// Kernel 4: out = W_w * y + W_b -> d_out f32 [B][C][N] (unchanged)
// ---------------------------------------------------------------------------
__global__ __launch_bounds__(256) void outproj_kernel(
    const u16* __restrict__ ybf, const float* __restrict__ Ww,
    const float* __restrict__ Wb, float* __restrict__ out)
{
  const int t = threadIdx.x;
  const int nt0 = blockIdx.x * 64;
  const int b = blockIdx.y;

  __shared__ __align__(16) u16 W_lds[128][136];
  __shared__ __align__(16) u16 y_lds[64][136];

  for (int i = 0; i < 16; ++i) {
    int s = t + i * 256;
    int row = s >> 5, c4 = s & 31;
    float4 v = *reinterpret_cast<const float4*>(Ww + row * 128 + c4 * 4);
    u32 lo = (u32)f2bf(v.x) | ((u32)f2bf(v.y) << 16);
    u32 hi = (u32)f2bf(v.z) | ((u32)f2bf(v.w) << 16);
    *reinterpret_cast<uint2*>(&W_lds[row][c4 * 4]) = make_uint2(lo, hi);
  }
#pragma unroll
  for (int i = 0; i < 4; ++i) {
    int s = t + i * 256; int row = s >> 4, cc8 = s & 15;
    uint4 v = *reinterpret_cast<const uint4*>(ybf + ((size_t)b * NN + nt0 + row) * CC + cc8 * 8);
    *reinterpret_cast<uint4*>(&y_lds[row][cc8 * 8]) = v;
  }
  __syncthreads();

  const int w_id = t >> 6, l = t & 63;
  const int lr = l & 15, lh = l >> 4;

  f32x4 acc[2][4];
#pragma unroll
  for (int rt = 0; rt < 2; ++rt)
#pragma unroll
    for (int nt = 0; nt < 4; ++nt) acc[rt][nt] = (f32x4){0.f, 0.f, 0.f, 0.f};
#pragma unroll
  for (int kc = 0; kc < 4; ++kc) {
    bf16x8 a0 = ldfrag(&W_lds[w_id * 32 + lr][kc * 32 + lh * 8]);
    bf16x8 a1 = ldfrag(&W_lds[w_id * 32 + 16 + lr][kc * 32 + lh * 8]);
#pragma unroll
    for (int nt = 0; nt < 4; ++nt) {
      bf16x8 bf = ldfrag(&y_lds[nt * 16 + lr][kc * 32 + lh * 8]);
      acc[0][nt] = mfma16(a0, bf, acc[0][nt]);
      acc[1][nt] = mfma16(a1, bf, acc[1][nt]);
    }
  }
#pragma unroll
  for (int rt = 0; rt < 2; ++rt)
#pragma unroll
    for (int r = 0; r < 4; ++r) {
      int c = w_id * 32 + rt * 16 + lh * 4 + r;
      float bv = Wb[c];
#pragma unroll
      for (int nt = 0; nt < 4; ++nt)
        out[((size_t)b * CC + c) * NN + nt0 + nt * 16 + lr] = acc[rt][nt][r] + bv;
    }
}

// ---------------------------------------------------------------------------
extern "C" void kernel_launch(void* const* d_in, const int* in_sizes, int n_in,
                              void* d_out, int out_size, void* d_ws, size_t ws_size,
                              hipStream_t stream) {
  const float* x0   = (const float*)d_in[0];
  const float* x1   = (const float*)d_in[1];
  const float* g_w  = (const float*)d_in[2];
  const float* g_b  = (const float*)d_in[3];
  const float* th_w = (const float*)d_in[4];
  const float* th_b = (const float*)d_in[5];
  const float* ph_w = (const float*)d_in[6];
  const float* ph_b = (const float*)d_in[7];
  const float* Ww   = (const float*)d_in[8];
  const float* Wb   = (const float*)d_in[9];

  char* ws = (char*)d_ws;
  u16* qws    = (u16*)(ws + 0);
  u16* kws    = (u16*)(ws + (size_t)4194304);
  u16* vws    = (u16*)(ws + (size_t)8388608);
  u16* ybf    = (u16*)(ws + (size_t)12582912);
  float* yacc = (float*)(ws + (size_t)16777216);
  float* mlp  = (float*)(ws + (size_t)50331648);

  dim3 gp(64, 4, 3);
  proj_kernel<<<gp, 256, 0, stream>>>(x0, x1, g_w, g_b, th_w, th_b, ph_w, ph_b,
                                      qws, kws, vws);
  dim3 ga(32, 4, NSEG);
  attn_kernel<<<ga, 256, 0, stream>>>(qws, kws, vws, yacc, mlp);
  combine_kernel<<<1024, 256, 0, stream>>>(yacc, mlp, ybf);
  dim3 go(64, 4);
  outproj_kernel<<<go, 256, 0, stream>>>(ybf, Ww, Wb, (float*)d_out);
}